// Round 9
// baseline (161.893 us; speedup 1.0000x reference)
//
#include <hip/hip_runtime.h>

// HybridQuantumNetQML — round 9: contiguous streaming reads + wave-private
// LDS transpose, barrier-free K-loop. Discriminator for H1 (read-pattern
// inefficiency) vs H2 (harness ws-fill drain interference).
//
// Keeps R7/R8's verified pieces verbatim: B-fragment build + K permutation
// (strip sg = 112 k padded to 128; pair pr=4T+q; feature base = 8*pr),
// MFMA 16x16x32 bf16, C/D->lg epilogue, qfc/sampler/log_softmax.
//
// New x path: wave owns 16 samples; per strip it reads 16 x 448 B as 7
// fully-contiguous 1-KB wave-instructions (lane -> chunk c=i*64+lane,
// sample=c/28, off=c%28 via magic mul), 2-strip register lookahead
// (rr[3][7]), writes into its PRIVATE LDS region (single buffer, 464-B row
// stride: fragment reads m*464 -> 20m mod 32 banks -> 2-way = free; no
// __syncthreads in the K-loop — same-wave LDS ordering via compiler
// lgkmcnt). Fragment read: float4 top at m*464 + 224r+16cq, bot +112 B.
//
// LDS: B-frags [0,28672) | staging 4x7424 [28672,58368) | qf [58368,59392)
//      | lg [59392,62208); rawW overlays [28672,60152) during phases 0/1
//      (dead before staging/qf/lg are first written). 62208 B -> 2 blk/CU.

typedef __attribute__((ext_vector_type(8))) short short8;
typedef __attribute__((ext_vector_type(4))) float floatx4;

__device__ __forceinline__ unsigned short f2bf(float f) {
    unsigned u = __float_as_uint(f);
    return (unsigned short)((u + 0x7FFFu + ((u >> 16) & 1u)) >> 16);
}

#define STG_OFF 28672
#define STG_WV  7424          // 16 rows * 464 B
#define QF_OFF  58368
#define LG_OFF  59392
#define SMEM_SZ 62208

__global__ __launch_bounds__(256, 2)
void qml_mfma(const float* __restrict__ x,
              const float* __restrict__ wm,     // (787,10) f32
              const float* __restrict__ bias,   // (10,)
              const float* __restrict__ sw,     // (4,)
              float* __restrict__ out,          // (B,10)
              int B)
{
    __shared__ __align__(16) char smem[SMEM_SZ];
    float* rawW = (float*)(smem + STG_OFF);    // phases 0/1 only
    float* qf   = (float*)(smem + QF_OFF);     // 64 x 4 f32
    float* lg   = (float*)(smem + LG_OFF);     // 64 x 11 f32

    const int t = threadIdx.x;
    const int lane = t & 63;
    const int wv = __builtin_amdgcn_readfirstlane((int)(t >> 6));
    const int g = blockIdx.x;

    // ---- per-thread staging map: chunk c = i*64+lane -> (sample s, off) ----
    const float* gp[7];
    int lofs[7];
#pragma unroll
    for (int i = 0; i < 7; ++i) {
        const int c = i * 64 + lane;
        const int s = (c * 37450) >> 20;       // c / 28 (exact for c < 448)
        const int off = c - 28 * s;
        int sgl = g * 64 + wv * 16 + s;
        if (sgl >= B) sgl = B - 1;
        gp[i] = x + (size_t)sgl * 784 + off * 4;
        lofs[i] = STG_OFF + wv * STG_WV + s * 464 + off * 16;
    }

    // ---- issue strips 0,1 loads EARLY (latency overlaps W staging) ----
    floatx4 rr[3][7];
#pragma unroll
    for (int i = 0; i < 7; ++i) rr[0][i] = *(const floatx4*)(gp[i]);
#pragma unroll
    for (int i = 0; i < 7; ++i) rr[1][i] = *(const floatx4*)(gp[i] + 112);

    // ---- phase 0: stage raw W -> LDS (coalesced) ----
    for (int i = t; i < 7870; i += 256) rawW[i] = wm[i];
    __syncthreads();

    // ---- phase 1: build B-fragments [R7 verbatim] ----
#pragma unroll
    for (int c = 0; c < 7; ++c) {
        const int CH = c * 256 + t;
        const int T = CH >> 6, L = CH & 63;
        const int n = L & 15, kq = L >> 4;
        short8 v;
#pragma unroll
        for (int j = 0; j < 8; ++j) {
            const int kh = 32 * T + kq * 8 + j;      // permuted k
            const int sg = kh >> 7, kl = kh & 127;   // strip, local slot
            float w = 0.0f;
            if (kl < 112 && n < 10) w = rawW[(112 * sg + kl) * 10 + n];
            v[j] = (short)f2bf(w);
        }
        *(short8*)(smem + CH * 16) = v;
    }
    __syncthreads();   // rawW dead; ONLY barrier before the epilogue

    // ---- write strip 0 into wave-private staging ----
#pragma unroll
    for (int i = 0; i < 7; ++i) *(floatx4*)(smem + lofs[i]) = rr[0][i];

    // ---- fragment constants ----
    const int m = lane & 15;
    const int q = lane >> 4;
    int offB[4], validT[4];
#pragma unroll
    for (int T = 0; T < 4; ++T) {
        const int pr = 4 * T + q;                // patch-pair within strip
        validT[T] = (pr < 14);
        const int r = (pr >= 7) ? 1 : 0;
        const int cq = (pr >= 7) ? (pr - 7) : pr;
        offB[T] = validT[T] ? (r * 224 + cq * 16) : 0;   // byte offset, top
    }
    const char* myrow = smem + STG_OFF + wv * STG_WV + m * 464;

    floatx4 acc = {0.f, 0.f, 0.f, 0.f};

    // ---- barrier-free strip loop ----
#pragma unroll
    for (int sg = 0; sg < 7; ++sg) {
#pragma unroll
        for (int T = 0; T < 4; ++T) {
            const floatx4 P = *(const floatx4*)(myrow + offB[T]);          // top
            const floatx4 Q = *(const floatx4*)(myrow + offB[T] + 112);    // bot
            const float c0 = __cosf(P.x), c1 = __cosf(P.y);
            const float c2 = __cosf(Q.x), c3 = __cosf(Q.y);
            const float c4 = __cosf(P.z), c5 = __cosf(P.w);
            const float c6 = __cosf(Q.z), c7 = __cosf(Q.w);
            const float f0 = c0, f1 = c0 * c1, f2 = c2, f3 = c2 * c3;
            const float f4 = c4, f5 = c4 * c5, f6 = c6, f7 = c6 * c7;

            if (sg == 0 && T == 0 && q == 0) {       // pair 0 = patches 0,1
                float* qd = qf + (wv * 16 + m) * 4;
                qd[0] = f0; qd[1] = f1; qd[2] = f2; qd[3] = f3;
            }

            short8 a;
            a[0] = (short)f2bf(f0); a[1] = (short)f2bf(f1);
            a[2] = (short)f2bf(f2); a[3] = (short)f2bf(f3);
            a[4] = (short)f2bf(f4); a[5] = (short)f2bf(f5);
            a[6] = (short)f2bf(f6); a[7] = (short)f2bf(f7);
            if (!validT[T]) a = (short8){0, 0, 0, 0, 0, 0, 0, 0};

            const short8 b8 = *(const short8*)(smem + ((4 * sg + T) * 64 + lane) * 16);
            acc = __builtin_amdgcn_mfma_f32_16x16x32_bf16(a, b8, acc, 0, 0, 0);
        }
        if (sg < 6) {
            const int ws = (sg + 1) % 3;             // strip sg+1 regs -> LDS
#pragma unroll
            for (int i = 0; i < 7; ++i) *(floatx4*)(smem + lofs[i]) = rr[ws][i];
            if (sg < 5) {
                const int ns = (sg + 2) % 3;         // issue strip sg+2 loads
#pragma unroll
                for (int i = 0; i < 7; ++i)
                    rr[ns][i] = *(const floatx4*)(gp[i] + (sg + 2) * 112);
            }
        }
    }

    // ---- epilogue [R8 verbatim; lg/qf relocated] ----
    {
        const int n = lane & 15;
        const int rbase = wv * 16 + (lane >> 4) * 4;   // C row = (lane>>4)*4+reg
        if (n < 10) {
#pragma unroll
            for (int r = 0; r < 4; ++r) lg[(rbase + r) * 11 + n] = acc[r];
        }
    }
    __syncthreads();

    // pass 1: add qfc/sampler/tail/bias
#pragma unroll
    for (int e = t; e < 640; e += 256) {
        const int s2 = e / 10, c2 = e - 10 * s2;
        float logit = lg[s2 * 11 + c2];
        const float q0 = qf[s2 * 4 + 0], q1 = qf[s2 * 4 + 1];
        const float q2 = qf[s2 * 4 + 2], q3 = qf[s2 * 4 + 3];

        const float f0 = __cosf(q0), f1 = __cosf(q1);
        const float f2 = __cosf(q2), f3 = __cosf(q3);
        const float qfc = (f0 + f0 * f1 + f2 + f2 * f3) * 0.25f;

        const float t0 = q0 + sw[0] + sw[2];
        const float t1 = q1 + sw[1] + sw[3];
        const float z0 = __cosf(t0);
        const float z1 = z0 * __cosf(t1);
        const float e0 = __expf(z0), e1 = __expf(z1);
        const float inv = 1.0f / (e0 + e1);

        const float* __restrict__ wt = wm + 7840;      // rows 784..786
        logit += bias[c2] + qfc * wt[c2] + (e0 * inv) * wt[10 + c2]
                          + (e1 * inv) * wt[20 + c2];
        lg[s2 * 11 + c2] = logit;
    }
    __syncthreads();

    // pass 2: log_softmax + coalesced store
#pragma unroll
    for (int e = t; e < 640; e += 256) {
        const int s2 = e / 10, c2 = e - 10 * s2;
        float mx = -3.4e38f;
#pragma unroll
        for (int k = 0; k < 10; ++k) mx = fmaxf(mx, lg[s2 * 11 + k]);
        float ss = 0.0f;
#pragma unroll
        for (int k = 0; k < 10; ++k) ss += __expf(lg[s2 * 11 + k] - mx);
        const float lse = __logf(ss) + mx;
        if (g * 64 + s2 < B)
            out[(size_t)g * 640 + e] = lg[s2 * 11 + c2] - lse;
    }
}

extern "C" void kernel_launch(void* const* d_in, const int* in_sizes, int n_in,
                              void* d_out, int out_size, void* d_ws, size_t ws_size,
                              hipStream_t stream) {
    const float* x    = (const float*)d_in[0];   // (B,1,28,28) f32
    const float* w    = (const float*)d_in[1];   // (787,10)    f32
    const float* bias = (const float*)d_in[2];   // (10,)       f32
    const float* sw   = (const float*)d_in[3];   // (4,)        f32
    float* out = (float*)d_out;                  // (B,10)      f32

    const int B = in_sizes[0] / 784;
    const int nblk = (B + 63) / 64;
    qml_mfma<<<nblk, 256, 0, stream>>>(x, w, bias, sw, out, B);
}

// Round 10
// 154.018 us; speedup vs baseline: 1.0511x; 1.0511x over previous
//
#include <hip/hip_runtime.h>

// HybridQuantumNetQML — round 10: R9 + NON-TEMPORAL x reads (single-bit A/B).
//
// Evidence: every rocprof-measured kernel ran at ~870 GB/s HBM fetch
// (R1 0.83, R3 0.88 @71% occ, R5 0.84 TB/s) regardless of occupancy,
// coalescing, barriers, or MFMA vs VALU -> throughput cap in TCC/MALL,
// hypothesized dirty-line pollution from the harness's 401MB ws-fill +
// 103MB x-restore immediately preceding the kernel. x is read-once ->
// nt loads (no cache allocation, no dirty-victim writebacks) should
// stream at HBM rate. Everything else is byte-identical to R9.

typedef __attribute__((ext_vector_type(8))) short short8;
typedef __attribute__((ext_vector_type(4))) float floatx4;

__device__ __forceinline__ unsigned short f2bf(float f) {
    unsigned u = __float_as_uint(f);
    return (unsigned short)((u + 0x7FFFu + ((u >> 16) & 1u)) >> 16);
}

#define STG_OFF 28672
#define STG_WV  7424          // 16 rows * 464 B
#define QF_OFF  58368
#define LG_OFF  59392
#define SMEM_SZ 62208

__global__ __launch_bounds__(256, 2)
void qml_mfma(const float* __restrict__ x,
              const float* __restrict__ wm,     // (787,10) f32
              const float* __restrict__ bias,   // (10,)
              const float* __restrict__ sw,     // (4,)
              float* __restrict__ out,          // (B,10)
              int B)
{
    __shared__ __align__(16) char smem[SMEM_SZ];
    float* rawW = (float*)(smem + STG_OFF);    // phases 0/1 only
    float* qf   = (float*)(smem + QF_OFF);     // 64 x 4 f32
    float* lg   = (float*)(smem + LG_OFF);     // 64 x 11 f32

    const int t = threadIdx.x;
    const int lane = t & 63;
    const int wv = __builtin_amdgcn_readfirstlane((int)(t >> 6));
    const int g = blockIdx.x;

    // ---- per-thread staging map: chunk c = i*64+lane -> (sample s, off) ----
    const float* gp[7];
    int lofs[7];
#pragma unroll
    for (int i = 0; i < 7; ++i) {
        const int c = i * 64 + lane;
        const int s = (c * 37450) >> 20;       // c / 28 (exact for c < 448)
        const int off = c - 28 * s;
        int sgl = g * 64 + wv * 16 + s;
        if (sgl >= B) sgl = B - 1;
        gp[i] = x + (size_t)sgl * 784 + off * 4;
        lofs[i] = STG_OFF + wv * STG_WV + s * 464 + off * 16;
    }

    // ---- issue strips 0,1 loads EARLY (nt: bypass cache allocation) ----
    floatx4 rr[3][7];
#pragma unroll
    for (int i = 0; i < 7; ++i)
        rr[0][i] = __builtin_nontemporal_load((const floatx4*)gp[i]);
#pragma unroll
    for (int i = 0; i < 7; ++i)
        rr[1][i] = __builtin_nontemporal_load((const floatx4*)(gp[i] + 112));

    // ---- phase 0: stage raw W -> LDS (coalesced, cached) ----
    for (int i = t; i < 7870; i += 256) rawW[i] = wm[i];
    __syncthreads();

    // ---- phase 1: build B-fragments [R7 verbatim] ----
#pragma unroll
    for (int c = 0; c < 7; ++c) {
        const int CH = c * 256 + t;
        const int T = CH >> 6, L = CH & 63;
        const int n = L & 15, kq = L >> 4;
        short8 v;
#pragma unroll
        for (int j = 0; j < 8; ++j) {
            const int kh = 32 * T + kq * 8 + j;      // permuted k
            const int sg = kh >> 7, kl = kh & 127;   // strip, local slot
            float w = 0.0f;
            if (kl < 112 && n < 10) w = rawW[(112 * sg + kl) * 10 + n];
            v[j] = (short)f2bf(w);
        }
        *(short8*)(smem + CH * 16) = v;
    }
    __syncthreads();   // rawW dead; ONLY barrier before the epilogue

    // ---- write strip 0 into wave-private staging ----
#pragma unroll
    for (int i = 0; i < 7; ++i) *(floatx4*)(smem + lofs[i]) = rr[0][i];

    // ---- fragment constants ----
    const int m = lane & 15;
    const int q = lane >> 4;
    int offB[4], validT[4];
#pragma unroll
    for (int T = 0; T < 4; ++T) {
        const int pr = 4 * T + q;                // patch-pair within strip
        validT[T] = (pr < 14);
        const int r = (pr >= 7) ? 1 : 0;
        const int cq = (pr >= 7) ? (pr - 7) : pr;
        offB[T] = validT[T] ? (r * 224 + cq * 16) : 0;   // byte offset, top
    }
    const char* myrow = smem + STG_OFF + wv * STG_WV + m * 464;

    floatx4 acc = {0.f, 0.f, 0.f, 0.f};

    // ---- barrier-free strip loop ----
#pragma unroll
    for (int sg = 0; sg < 7; ++sg) {
#pragma unroll
        for (int T = 0; T < 4; ++T) {
            const floatx4 P = *(const floatx4*)(myrow + offB[T]);          // top
            const floatx4 Q = *(const floatx4*)(myrow + offB[T] + 112);    // bot
            const float c0 = __cosf(P.x), c1 = __cosf(P.y);
            const float c2 = __cosf(Q.x), c3 = __cosf(Q.y);
            const float c4 = __cosf(P.z), c5 = __cosf(P.w);
            const float c6 = __cosf(Q.z), c7 = __cosf(Q.w);
            const float f0 = c0, f1 = c0 * c1, f2 = c2, f3 = c2 * c3;
            const float f4 = c4, f5 = c4 * c5, f6 = c6, f7 = c6 * c7;

            if (sg == 0 && T == 0 && q == 0) {       // pair 0 = patches 0,1
                float* qd = qf + (wv * 16 + m) * 4;
                qd[0] = f0; qd[1] = f1; qd[2] = f2; qd[3] = f3;
            }

            short8 a;
            a[0] = (short)f2bf(f0); a[1] = (short)f2bf(f1);
            a[2] = (short)f2bf(f2); a[3] = (short)f2bf(f3);
            a[4] = (short)f2bf(f4); a[5] = (short)f2bf(f5);
            a[6] = (short)f2bf(f6); a[7] = (short)f2bf(f7);
            if (!validT[T]) a = (short8){0, 0, 0, 0, 0, 0, 0, 0};

            const short8 b8 = *(const short8*)(smem + ((4 * sg + T) * 64 + lane) * 16);
            acc = __builtin_amdgcn_mfma_f32_16x16x32_bf16(a, b8, acc, 0, 0, 0);
        }
        if (sg < 6) {
            const int ws = (sg + 1) % 3;             // strip sg+1 regs -> LDS
#pragma unroll
            for (int i = 0; i < 7; ++i) *(floatx4*)(smem + lofs[i]) = rr[ws][i];
            if (sg < 5) {
                const int ns = (sg + 2) % 3;         // issue strip sg+2 loads (nt)
#pragma unroll
                for (int i = 0; i < 7; ++i)
                    rr[ns][i] = __builtin_nontemporal_load(
                        (const floatx4*)(gp[i] + (sg + 2) * 112));
            }
        }
    }

    // ---- epilogue [R9 verbatim] ----
    {
        const int n = lane & 15;
        const int rbase = wv * 16 + (lane >> 4) * 4;   // C row = (lane>>4)*4+reg
        if (n < 10) {
#pragma unroll
            for (int r = 0; r < 4; ++r) lg[(rbase + r) * 11 + n] = acc[r];
        }
    }
    __syncthreads();

    // pass 1: add qfc/sampler/tail/bias
#pragma unroll
    for (int e = t; e < 640; e += 256) {
        const int s2 = e / 10, c2 = e - 10 * s2;
        float logit = lg[s2 * 11 + c2];
        const float q0 = qf[s2 * 4 + 0], q1 = qf[s2 * 4 + 1];
        const float q2 = qf[s2 * 4 + 2], q3 = qf[s2 * 4 + 3];

        const float f0 = __cosf(q0), f1 = __cosf(q1);
        const float f2 = __cosf(q2), f3 = __cosf(q3);
        const float qfc = (f0 + f0 * f1 + f2 + f2 * f3) * 0.25f;

        const float t0 = q0 + sw[0] + sw[2];
        const float t1 = q1 + sw[1] + sw[3];
        const float z0 = __cosf(t0);
        const float z1 = z0 * __cosf(t1);
        const float e0 = __expf(z0), e1 = __expf(z1);
        const float inv = 1.0f / (e0 + e1);

        const float* __restrict__ wt = wm + 7840;      // rows 784..786
        logit += bias[c2] + qfc * wt[c2] + (e0 * inv) * wt[10 + c2]
                          + (e1 * inv) * wt[20 + c2];
        lg[s2 * 11 + c2] = logit;
    }
    __syncthreads();

    // pass 2: log_softmax + coalesced store
#pragma unroll
    for (int e = t; e < 640; e += 256) {
        const int s2 = e / 10, c2 = e - 10 * s2;
        float mx = -3.4e38f;
#pragma unroll
        for (int k = 0; k < 10; ++k) mx = fmaxf(mx, lg[s2 * 11 + k]);
        float ss = 0.0f;
#pragma unroll
        for (int k = 0; k < 10; ++k) ss += __expf(lg[s2 * 11 + k] - mx);
        const float lse = __logf(ss) + mx;
        if (g * 64 + s2 < B)
            out[(size_t)g * 640 + e] = lg[s2 * 11 + c2] - lse;
    }
}

extern "C" void kernel_launch(void* const* d_in, const int* in_sizes, int n_in,
                              void* d_out, int out_size, void* d_ws, size_t ws_size,
                              hipStream_t stream) {
    const float* x    = (const float*)d_in[0];   // (B,1,28,28) f32
    const float* w    = (const float*)d_in[1];   // (787,10)    f32
    const float* bias = (const float*)d_in[2];   // (10,)       f32
    const float* sw   = (const float*)d_in[3];   // (4,)        f32
    float* out = (float*)d_out;                  // (B,10)      f32

    const int B = in_sizes[0] / 784;
    const int nblk = (B + 63) / 64;
    qml_mfma<<<nblk, 256, 0, stream>>>(x, w, bias, sw, out, B);
}